// Round 2
// baseline (366.812 us; speedup 1.0000x reference)
//
#include <hip/hip_runtime.h>
#include <hip/hip_bf16.h>
#include <math.h>

// Problem constants
#define N_ 256
#define C_ 256
#define V_ 25
#define T_ 20
#define C4_ 64
#define O_ 256
#define VT_ 500
#define EPS_ 1e-5f

typedef unsigned short ushort_t;
typedef unsigned short us4 __attribute__((ext_vector_type(4)));
typedef short short8 __attribute__((ext_vector_type(8)));
typedef float f32x4 __attribute__((ext_vector_type(4)));

__device__ __forceinline__ float bf2f(ushort_t u) {
    unsigned int v = ((unsigned int)u) << 16;
    return __builtin_bit_cast(float, v);
}
__device__ __forceinline__ ushort_t f2bf(float f) {
    unsigned int u = __builtin_bit_cast(unsigned int, f);
    unsigned int r = u + 0x7fffu + ((u >> 16) & 1u);
    return (ushort_t)(r >> 16);
}

// LDS-only barrier: drain lgkmcnt but leave vmcnt (private-register global
// loads) in flight across the barrier. Safe: the only cross-thread state is
// LDS (fully drained) — global loads land in per-thread registers.
__device__ __forceinline__ void bar_lds() {
    __builtin_amdgcn_sched_barrier(0);
    asm volatile("s_waitcnt lgkmcnt(0)" ::: "memory");
    __builtin_amdgcn_s_barrier();
    __builtin_amdgcn_sched_barrier(0);
}

// ---------------- Kernel 1: pool (coalesced) + Wc2->bf16 prep ----------------
// Blocks 0..8191: 8 nc-rows each. Blocks 8192..8255: Wc2 convert.
__global__ __launch_bounds__(256) void k_pool(const float* __restrict__ x,
                                              float* __restrict__ pooled,
                                              const float* __restrict__ Wc2,
                                              ushort_t* __restrict__ wbf) {
    int tid = threadIdx.x;
    if (blockIdx.x >= 8192) {
        int i = (blockIdx.x - 8192) * 256 + tid;     // vec4 index, 16384 total
        f32x4 v = ((const f32x4*)Wc2)[i];
        us4 o; o.x = f2bf(v.x); o.y = f2bf(v.y); o.z = f2bf(v.z); o.w = f2bf(v.w);
        ((us4*)wbf)[i] = o;
        return;
    }
    __shared__ float xs[8][504];
    const f32x4* src = (const f32x4*)(x + (size_t)blockIdx.x * 8 * VT_);
    // 8 rows x 500 floats = 1000 vec4, fully coalesced (rows contiguous)
    for (int i = tid; i < 1000; i += 256) {
        int r = i / 125, cidx = (i % 125) * 4;
        *(f32x4*)&xs[r][cidx] = src[i];
    }
    __syncthreads();
    if (tid < 160) {
        int r = tid / 20, t = tid % 20;
        float s = 0.f;
#pragma unroll
        for (int v = 0; v < V_; ++v) s += xs[r][v * T_ + t];
        pooled[blockIdx.x * 160 + tid] = s * 0.04f;   // pooled[nc][t]
    }
}

// ---------------- Kernel 2: G + L branches per n ----------------
__global__ __launch_bounds__(256) void k_gl(const float* __restrict__ pooled,
                                            const float* __restrict__ Wg1,
                                            const float* __restrict__ Wg2,
                                            const float* __restrict__ Wl1,
                                            const float* __restrict__ Wl2,
                                            const float* __restrict__ bng,
                                            const float* __restrict__ bnl,
                                            float* __restrict__ kern,
                                            float* __restrict__ l2out) {
    __shared__ float pp[C_][22];
    __shared__ float wg1[800];
    __shared__ float wg2[120];
    __shared__ float sg[40], bg[40];
    __shared__ float ls[C4_][20];
    __shared__ float sl[C4_], bl[C4_];
    int tid = threadIdx.x;
    int n = blockIdx.x;

    for (int i = tid; i < 800; i += 256) wg1[i] = Wg1[i];
    if (tid < 120) wg2[tid] = Wg2[tid];
    if (tid < 40) {
        float g = bng[tid], b = bng[40 + tid];
        float m = bng[80 + tid], v = bng[120 + tid];
        float s = g * rsqrtf(v + EPS_);
        sg[tid] = s; bg[tid] = b - m * s;
    }
    if (tid < C4_) {
        float g = bnl[tid], b = bnl[64 + tid];
        float m = bnl[128 + tid], v = bnl[192 + tid];
        float s = g * rsqrtf(v + EPS_);
        sl[tid] = s; bl[tid] = b - m * s;
    }
    // pooled slab for this n: 256x20 = 1280 vec4, coalesced
    {
        const f32x4* pn = (const f32x4*)(pooled + n * (C_ * T_));
#pragma unroll
        for (int q = 0; q < 5; ++q) {
            int id = q * 256 + tid;
            int c = id / 5, qq = id % 5;
            f32x4 v = pn[id];
            pp[c][qq * 4 + 1] = v.x; pp[c][qq * 4 + 2] = v.y;
            pp[c][qq * 4 + 3] = v.z; pp[c][qq * 4 + 4] = v.w;
        }
        pp[tid][0] = 0.f; pp[tid][21] = 0.f;
    }
    __syncthreads();

    // G branch (thread = c)
    {
        int c = tid;
        float p[20];
#pragma unroll
        for (int t = 0; t < 20; ++t) p[t] = pp[c][t + 1];
        float l0 = 0.f, l1 = 0.f, l2 = 0.f;
#pragma unroll 4
        for (int j = 0; j < 40; ++j) {
            float h = 0.f;
#pragma unroll
            for (int t = 0; t < 20; ++t) h = fmaf(wg1[j * 20 + t], p[t], h);
            h = fmaxf(fmaf(h, sg[j], bg[j]), 0.f);
            l0 = fmaf(wg2[j], h, l0);
            l1 = fmaf(wg2[40 + j], h, l1);
            l2 = fmaf(wg2[80 + j], h, l2);
        }
        float mx = fmaxf(l0, fmaxf(l1, l2));
        float e0 = __expf(l0 - mx), e1 = __expf(l1 - mx), e2 = __expf(l2 - mx);
        float inv = 1.f / (e0 + e1 + e2);
        float* kp = kern + (n * C_ + c) * 3;
        kp[0] = e0 * inv; kp[1] = e1 * inv; kp[2] = e2 * inv;
    }

    // L conv1 (thread = (c4, t-group))
    {
        int c4 = tid >> 2;
        int t0 = (tid & 3) * 5;
        float acc0 = 0.f, acc1 = 0.f, acc2 = 0.f, acc3 = 0.f, acc4 = 0.f;
        const float* w = Wl1 + c4 * (C_ * 3);
#pragma unroll 8
        for (int c = 0; c < C_; ++c) {
            float w0 = w[c * 3 + 0];
            float w1 = w[c * 3 + 1];
            float w2 = w[c * 3 + 2];
            float a0 = pp[c][t0 + 0], a1 = pp[c][t0 + 1], a2 = pp[c][t0 + 2];
            float a3 = pp[c][t0 + 3], a4 = pp[c][t0 + 4], a5 = pp[c][t0 + 5];
            float a6 = pp[c][t0 + 6];
            acc0 = fmaf(w0, a0, fmaf(w1, a1, fmaf(w2, a2, acc0)));
            acc1 = fmaf(w0, a1, fmaf(w1, a2, fmaf(w2, a3, acc1)));
            acc2 = fmaf(w0, a2, fmaf(w1, a3, fmaf(w2, a4, acc2)));
            acc3 = fmaf(w0, a3, fmaf(w1, a4, fmaf(w2, a5, acc3)));
            acc4 = fmaf(w0, a4, fmaf(w1, a5, fmaf(w2, a6, acc4)));
        }
        float s = sl[c4], b = bl[c4];
        ls[c4][t0 + 0] = fmaxf(fmaf(acc0, s, b), 0.f);
        ls[c4][t0 + 1] = fmaxf(fmaf(acc1, s, b), 0.f);
        ls[c4][t0 + 2] = fmaxf(fmaf(acc2, s, b), 0.f);
        ls[c4][t0 + 3] = fmaxf(fmaf(acc3, s, b), 0.f);
        ls[c4][t0 + 4] = fmaxf(fmaf(acc4, s, b), 0.f);
    }
    __syncthreads();

    // L conv2 + sigmoid (thread = c)
    {
        int c = tid;
        float acc[20];
#pragma unroll
        for (int t = 0; t < 20; ++t) acc[t] = 0.f;
        const float* w = Wl2 + c * C4_;
#pragma unroll 4
        for (int c4 = 0; c4 < C4_; ++c4) {
            float wv = w[c4];
#pragma unroll
            for (int t = 0; t < 20; ++t) acc[t] = fmaf(wv, ls[c4][t], acc[t]);
        }
        f32x4* o = (f32x4*)(l2out + (n * C_ + c) * T_);
#pragma unroll
        for (int q = 0; q < 5; ++q) {
            f32x4 v;
            v.x = 1.f / (1.f + __expf(-acc[q*4+0]));
            v.y = 1.f / (1.f + __expf(-acc[q*4+1]));
            v.z = 1.f / (1.f + __expf(-acc[q*4+2]));
            v.w = 1.f / (1.f + __expf(-acc[q*4+3]));
            o[q] = v;
        }
    }
}

// ---------------- Kernel 3: dyn-conv + bn1 + MFMA 1x1 + bn2, grid (5, N) ----------------
#define YSTRIDE 264   // bf16 elems per yT row: 528 B, 16B-aligned, 2-way-bank (free)

// One GEMM pass over a subset of p-tiles. acc = 4 mt x NT tiles -> <=64 VGPRs.
// Epilogue: bn2 params via __shfl (lane L of wave w owns channel 64w+L),
// direct scalar stores (16 lanes -> one fully-covered 64B line, 4 lines/instr).
template <int NT>
__device__ __forceinline__ void gemm_pass(const ushort_t* __restrict__ yT,
                                          const ushort_t* __restrict__ wbf,
                                          float* __restrict__ outn,
                                          const int (&ctb)[NT], int ov_idx,
                                          int obase, int mrow, int kof, int prow,
                                          float s2, float b2) {
    f32x4 acc[4][NT];
#pragma unroll
    for (int mt = 0; mt < 4; ++mt)
#pragma unroll
        for (int j = 0; j < NT; ++j) acc[mt][j] = (f32x4){0.f, 0.f, 0.f, 0.f};

#pragma unroll 1
    for (int kk = 0; kk < C_; kk += 32) {
        short8 af[4];
        short8 bfr[NT];
#pragma unroll
        for (int mt = 0; mt < 4; ++mt)
            af[mt] = *(const short8*)(wbf + (obase + mt * 16 + mrow) * C_ + kk + kof);
#pragma unroll
        for (int j = 0; j < NT; ++j)
            bfr[j] = *(const short8*)(yT + (ctb[j] + mrow) * YSTRIDE + kk + kof);
#pragma unroll
        for (int mt = 0; mt < 4; ++mt)
#pragma unroll
            for (int j = 0; j < NT; ++j)
                acc[mt][j] = __builtin_amdgcn_mfma_f32_16x16x32_bf16(af[mt], bfr[j], acc[mt][j], 0, 0, 0);
    }

#pragma unroll
    for (int mt = 0; mt < 4; ++mt) {
#pragma unroll
        for (int r = 0; r < 4; ++r) {
            int lsrc = mt * 16 + prow + r;            // lane owning channel obase+lsrc
            float s2w = __shfl(s2, lsrc);
            float b2w = __shfl(b2, lsrc);
            float* orow = outn + (size_t)(obase + lsrc) * VT_;
#pragma unroll
            for (int j = 0; j < NT; ++j) {
                bool skip = (j == ov_idx) && (mrow < 12);   // overlap tile: dup p 84..95
                if (!skip) {
                    float vr = fmaxf(fmaf(acc[mt][j][r], s2w, b2w), 0.f);
                    orow[ctb[j] + mrow] = vr;
                }
            }
        }
    }
}

__global__ __launch_bounds__(256, 3) void k_main(const float* __restrict__ x,
                                                 const ushort_t* __restrict__ wbf,
                                                 const float* __restrict__ bn1p,
                                                 const float* __restrict__ bn2p,
                                                 const float* __restrict__ kern,
                                                 const float* __restrict__ l2g,
                                                 float* __restrict__ out) {
    // 100 x 264 bf16 = 52800 B -> 3 blocks/CU (was 61440 -> 2/CU).
    // __launch_bounds__(256,3): LDS caps occupancy at 3 blocks/CU anyway;
    // demanding 4 would only squeeze VGPRs to 128 and risk spill for no gain.
    __shared__ __align__(16) ushort_t yT[100 * YSTRIDE];

    int tid = threadIdx.x;
    int n = blockIdx.y;
    int vblk = blockIdx.x;
    const float* xn = x + (size_t)n * (C_ * V_ * T_) + vblk * 100;

    // per-c params (thread = c); bn2 scale/bias stay in this lane's registers
    float s1, b1, k0, k1, k2, s2, b2, l2r[20];
    {
        int c = tid;
        float g1 = bn1p[c], be1 = bn1p[256 + c];
        float m1 = bn1p[512 + c], v1 = bn1p[768 + c];
        s1 = g1 * rsqrtf(v1 + EPS_);
        b1 = be1 - m1 * s1;
        float g2 = bn2p[c], be2 = bn2p[256 + c];
        float m2 = bn2p[512 + c], v2 = bn2p[768 + c];
        s2 = g2 * rsqrtf(v2 + EPS_);
        b2 = be2 - m2 * s2;
        const float* kp = kern + (n * C_ + c) * 3;
        k0 = kp[0]; k1 = kp[1]; k2 = kp[2];
        const f32x4* lp = (const f32x4*)(l2g + (n * C_ + c) * T_);
#pragma unroll
        for (int q = 0; q < 5; ++q) {
            f32x4 v = lp[q];
            l2r[q*4+0] = v.x; l2r[q*4+1] = v.y; l2r[q*4+2] = v.z; l2r[q*4+3] = v.w;
        }
    }

    // invariant per-q offsets: id -> (c = id/5, qq = id%5)
    int offg[5], offs[5];
#pragma unroll
    for (int q = 0; q < 5; ++q) {
        int id = q * 256 + tid;
        int c = id / 5, qq = id % 5;
        offg[q] = c * VT_ + qq * 4;   // global: + vl*20
        offs[q] = c * 20 + qq * 4;    // ushort idx within xs
    }

    // ---- staging: software-pipelined (loads for vl+1 in flight across the
    //      lgkmcnt-only barriers), LDS(bf16) transpose -> conv -> yT ----
    f32x4 ld[5];
#pragma unroll
    for (int q = 0; q < 5; ++q) ld[q] = *(const f32x4*)(xn + offg[q]);

    for (int vl = 0; vl < 5; ++vl) {
        f32x4 ldn[5];
        if (vl < 4) {
#pragma unroll
            for (int q = 0; q < 5; ++q)
                ldn[q] = *(const f32x4*)(xn + offg[q] + (vl + 1) * 20);
        }
        ushort_t* xs = yT + vl * 20 * YSTRIDE;   // aliases this vl's future yT rows
#pragma unroll
        for (int q = 0; q < 5; ++q) {
            us4 o; o.x = f2bf(ld[q].x); o.y = f2bf(ld[q].y);
            o.z = f2bf(ld[q].z); o.w = f2bf(ld[q].w);
            *(us4*)(xs + offs[q]) = o;
        }
        bar_lds();                                // xs visible; vmcnt NOT drained
        float a[22];
        a[0] = 0.f; a[21] = 0.f;
        {
            const ushort_t* xrow = xs + tid * 20;
#pragma unroll
            for (int qq = 0; qq < 5; ++qq) {
                us4 u = *(const us4*)(xrow + qq * 4);
                a[qq*4 + 1] = bf2f(u.x) + l2r[qq*4 + 0];
                a[qq*4 + 2] = bf2f(u.y) + l2r[qq*4 + 1];
                a[qq*4 + 3] = bf2f(u.z) + l2r[qq*4 + 2];
                a[qq*4 + 4] = bf2f(u.w) + l2r[qq*4 + 3];
            }
        }
        bar_lds();                                // all xs reads done; region becomes yT
        {
            ushort_t* yrow = yT + vl * 20 * YSTRIDE + tid;
#pragma unroll
            for (int t = 0; t < 20; ++t) {
                float z = fmaf(k0, a[t], fmaf(k1, a[t + 1], k2 * a[t + 2]));
                yrow[t * YSTRIDE] = f2bf(fmaxf(fmaf(z, s1, b1), 0.f));
            }
        }
        if (vl < 4) {
#pragma unroll
            for (int q = 0; q < 5; ++q) ld[q] = ldn[q];
        }
    }
    bar_lds();   // yT complete for all waves

    // ---- MFMA: out[o,p] = sum_c Wc2[o,c] * y[c,p], split into 2 ct-passes ----
    int lane = tid & 63;
    int wave = tid >> 6;
    int mrow = lane & 15;
    int kof = (lane >> 4) * 8;
    int prow = (lane >> 4) * 4;
    int obase = wave * 64;
    float* outn = out + (size_t)n * (O_ * VT_) + vblk * 100;

    {
        const int ctb0[4] = {0, 16, 32, 48};      // p 0..63
        gemm_pass<4>(yT, wbf, outn, ctb0, -1, obase, mrow, kof, prow, s2, b2);
    }
    {
        const int ctb1[3] = {64, 80, 84};         // p 64..95 + overlap tile (96..99)
        gemm_pass<3>(yT, wbf, outn, ctb1, 2, obase, mrow, kof, prow, s2, b2);
    }
}

extern "C" void kernel_launch(void* const* d_in, const int* in_sizes, int n_in,
                              void* d_out, int out_size, void* d_ws, size_t ws_size,
                              hipStream_t stream) {
    const float* x   = (const float*)d_in[0];
    const float* Wg1 = (const float*)d_in[1];
    const float* Wg2 = (const float*)d_in[2];
    const float* Wl1 = (const float*)d_in[3];
    const float* Wl2 = (const float*)d_in[4];
    const float* Wc2 = (const float*)d_in[5];
    const float* bng = (const float*)d_in[6];
    const float* bnl = (const float*)d_in[7];
    const float* bn1p = (const float*)d_in[8];
    const float* bn2p = (const float*)d_in[9];
    float* out = (float*)d_out;

    float* ws = (float*)d_ws;
    float* pooled = ws;                                  // N*C*T = 1310720 f
    float* kern   = ws + 1310720;                        // N*C*3 = 196608 f
    float* l2g    = ws + 1310720 + 196608;               // N*C*T = 1310720 f
    ushort_t* wbf = (ushort_t*)(ws + 1310720 + 196608 + 1310720);  // O*C bf16

    k_pool<<<dim3(8256), dim3(256), 0, stream>>>(x, pooled, Wc2, wbf);
    k_gl<<<dim3(N_), dim3(256), 0, stream>>>(pooled, Wg1, Wg2, Wl1, Wl2, bng, bnl, kern, l2g);
    k_main<<<dim3(5, N_), dim3(256), 0, stream>>>(x, wbf, bn1p, bn2p, kern, l2g, out);
}

// Round 3
// 352.487 us; speedup vs baseline: 1.0406x; 1.0406x over previous
//
#include <hip/hip_runtime.h>
#include <hip/hip_bf16.h>
#include <math.h>

// Problem constants
#define N_ 256
#define C_ 256
#define V_ 25
#define T_ 20
#define C4_ 64
#define O_ 256
#define VT_ 500
#define EPS_ 1e-5f

typedef unsigned short ushort_t;
typedef unsigned short us4 __attribute__((ext_vector_type(4)));
typedef short short8 __attribute__((ext_vector_type(8)));
typedef float f32x4 __attribute__((ext_vector_type(4)));

__device__ __forceinline__ float bf2f(ushort_t u) {
    unsigned int v = ((unsigned int)u) << 16;
    return __builtin_bit_cast(float, v);
}
__device__ __forceinline__ ushort_t f2bf(float f) {
    unsigned int u = __builtin_bit_cast(unsigned int, f);
    unsigned int r = u + 0x7fffu + ((u >> 16) & 1u);
    return (ushort_t)(r >> 16);
}

// LDS-only barrier: drain lgkmcnt but leave vmcnt (private-register global
// loads) in flight across the barrier.
__device__ __forceinline__ void bar_lds() {
    __builtin_amdgcn_sched_barrier(0);
    asm volatile("s_waitcnt lgkmcnt(0)" ::: "memory");
    __builtin_amdgcn_s_barrier();
    __builtin_amdgcn_sched_barrier(0);
}

// ---------------- Kernel 1: pool (coalesced) + weight prep ----------------
// Blocks 0..8191: pooling (8 nc-rows each).
// 8192..8255: Wc2 -> bf16.  8256..8271: Wl2 -> bf16.  8272..8463: Wl1 -> awl bf16 (permuted).
__global__ __launch_bounds__(256) void k_pool(const float* __restrict__ x,
                                              float* __restrict__ pooled,
                                              const float* __restrict__ Wc2,
                                              ushort_t* __restrict__ wbf,
                                              const float* __restrict__ Wl1,
                                              ushort_t* __restrict__ awl,
                                              const float* __restrict__ Wl2,
                                              ushort_t* __restrict__ wl2bf) {
    int tid = threadIdx.x;
    if (blockIdx.x >= 8272) {
        // awl[c4*768 + k*256 + c] = bf16(Wl1[(c4*256+c)*3 + k]); 49152 elems
        int o = (blockIdx.x - 8272) * 256 + tid;
        int c4 = o / 768;
        int rem = o - c4 * 768;
        int k = rem >> 8, c = rem & 255;
        awl[o] = f2bf(Wl1[(c4 * 256 + c) * 3 + k]);
        return;
    }
    if (blockIdx.x >= 8256) {
        int i = (blockIdx.x - 8256) * 256 + tid;     // us4 index, 4096 total
        f32x4 v = ((const f32x4*)Wl2)[i];
        us4 o; o.x = f2bf(v.x); o.y = f2bf(v.y); o.z = f2bf(v.z); o.w = f2bf(v.w);
        ((us4*)wl2bf)[i] = o;
        return;
    }
    if (blockIdx.x >= 8192) {
        int i = (blockIdx.x - 8192) * 256 + tid;     // us4 index, 16384 total
        f32x4 v = ((const f32x4*)Wc2)[i];
        us4 o; o.x = f2bf(v.x); o.y = f2bf(v.y); o.z = f2bf(v.z); o.w = f2bf(v.w);
        ((us4*)wbf)[i] = o;
        return;
    }
    __shared__ float xs[8][504];
    const f32x4* src = (const f32x4*)(x + (size_t)blockIdx.x * 8 * VT_);
    for (int i = tid; i < 1000; i += 256) {
        int r = i / 125, cidx = (i % 125) * 4;
        *(f32x4*)&xs[r][cidx] = src[i];
    }
    __syncthreads();
    if (tid < 160) {
        int r = tid / 20, t = tid % 20;
        float s = 0.f;
#pragma unroll
        for (int v = 0; v < V_; ++v) s += xs[r][v * T_ + t];
        pooled[blockIdx.x * 160 + tid] = s * 0.04f;   // pooled[nc][t]
    }
}

// ---------------- Kernel 2: G (VALU, uniform weights) + L (MFMA) per n ----------------
// LDS: pp[256][22] f32 (22528) | sl/bl f32[64]x2 (512) | lsT 32x128B bf16 (4096)
//      | bpadT 32x1536B bf16 (49152)  -> total 76288 B
__global__ __launch_bounds__(256) void k_gl(const float* __restrict__ pooled,
                                            const float* __restrict__ Wg1,
                                            const float* __restrict__ Wg2,
                                            const float* __restrict__ bng,
                                            const float* __restrict__ bnl,
                                            const ushort_t* __restrict__ awl,
                                            const ushort_t* __restrict__ wl2bf,
                                            float* __restrict__ kern,
                                            float* __restrict__ l2out) {
    __shared__ __align__(16) char smem[76288];
    float (*pp)[22] = (float (*)[22])smem;
    float* sl = (float*)(smem + 22528);
    float* bl = (float*)(smem + 22528 + 256);
    char* lsT = smem + 23040;    // 32 rows x 128 B, bf16 [t][c4], XOR-swizzled
    char* bpt = smem + 27136;    // 32 rows x 1536 B, bf16 [t][k*256+c], XOR-swizzled

    int tid = threadIdx.x;
    int n = blockIdx.x;

    // pooled slab -> pp (coalesced)
    {
        const f32x4* pn = (const f32x4*)(pooled + n * (C_ * T_));
#pragma unroll
        for (int q = 0; q < 5; ++q) {
            int id = q * 256 + tid;
            int c = id / 5, qq = id % 5;
            f32x4 v = pn[id];
            pp[c][qq * 4 + 0] = v.x; pp[c][qq * 4 + 1] = v.y;
            pp[c][qq * 4 + 2] = v.z; pp[c][qq * 4 + 3] = v.w;
        }
    }
    if (tid < C4_) {
        float g = bnl[tid], b = bnl[64 + tid];
        float m = bnl[128 + tid], v = bnl[192 + tid];
        float s = g * rsqrtf(v + EPS_);
        sl[tid] = s; bl[tid] = b - m * s;
    }
    // zero lsT rows 20..31 (bytes 2560..4096); zeros invariant under in-row swizzle
    {
        unsigned int* z = (unsigned int*)lsT;
        for (int i = tid; i < 384; i += 256) z[640 + i] = 0u;
    }
    __syncthreads();

    // own pooled row into regs
    float p[20];
#pragma unroll
    for (int t = 0; t < 20; ++t) p[t] = pp[tid][t];

    // G branch (thread = c); weights read with wave-uniform addresses -> s_load
    {
        float l0 = 0.f, l1 = 0.f, l2 = 0.f;
#pragma unroll 4
        for (int j = 0; j < 40; ++j) {
            float h = 0.f;
#pragma unroll
            for (int t = 0; t < 20; ++t) h = fmaf(Wg1[j * 20 + t], p[t], h);
            float g = bng[j], b = bng[40 + j];
            float m = bng[80 + j], v = bng[120 + j];
            float s = g * rsqrtf(v + EPS_);
            h = fmaxf(fmaf(h, s, b - m * s), 0.f);
            l0 = fmaf(Wg2[j], h, l0);
            l1 = fmaf(Wg2[40 + j], h, l1);
            l2 = fmaf(Wg2[80 + j], h, l2);
        }
        float mx = fmaxf(l0, fmaxf(l1, l2));
        float e0 = __expf(l0 - mx), e1 = __expf(l1 - mx), e2 = __expf(l2 - mx);
        float inv = 1.f / (e0 + e1 + e2);
        float* kp = kern + (n * C_ + tid) * 3;
        kp[0] = e0 * inv; kp[1] = e1 * inv; kp[2] = e2 * inv;
    }

    // build bpadT[t][k*256+c] = pooled[c][t+k-1] (0 outside), swizzled b16 writes
    {
        int c = tid;
#pragma unroll
        for (int k = 0; k < 3; ++k) {
            int col2base = (k * 256 + c) * 2;
#pragma unroll
            for (int t = 0; t < 20; ++t) {
                int i = t + k - 1;
                float v = (i >= 0 && i < 20) ? p[i] : 0.f;
                int byte = t * 1536 + (col2base ^ ((t & 7) << 4));
                *(ushort_t*)(bpt + byte) = f2bf(v);
            }
        }
    }
    __syncthreads();

    int lane = tid & 63, wave = tid >> 6;
    int mrow = lane & 15, kof = (lane >> 4) * 8, prow = (lane >> 4) * 4;

    // conv1 MFMA: L[c4][t] = sum_K awl[c4][K] * bpadT[t][K], K = 768
    {
        f32x4 acc0 = (f32x4){0.f, 0.f, 0.f, 0.f};
        f32x4 acc1 = (f32x4){0.f, 0.f, 0.f, 0.f};
        int swz = ((mrow & 7) << 4);
#pragma unroll 4
        for (int kk = 0; kk < 768; kk += 32) {
            short8 af = *(const short8*)(awl + (wave * 16 + mrow) * 768 + kk + kof);
            short8 b0 = *(const short8*)(bpt + mrow * 1536 + (((kk + kof) * 2) ^ swz));
            short8 b1 = *(const short8*)(bpt + (16 + mrow) * 1536 + (((kk + kof) * 2) ^ swz));
            acc0 = __builtin_amdgcn_mfma_f32_16x16x32_bf16(af, b0, acc0, 0, 0, 0);
            acc1 = __builtin_amdgcn_mfma_f32_16x16x32_bf16(af, b1, acc1, 0, 0, 0);
        }
        // bn + relu -> lsT[t][c4] bf16 (swizzled)
        f32x4 sv = *(const f32x4*)(sl + wave * 16 + prow);
        f32x4 bv = *(const f32x4*)(bl + wave * 16 + prow);
#pragma unroll
        for (int nt = 0; nt < 2; ++nt) {
            int t = nt * 16 + (lane & 15);
            if (t < 20) {
                f32x4 a = nt ? acc1 : acc0;
#pragma unroll
                for (int r = 0; r < 4; ++r) {
                    int c4 = wave * 16 + prow + r;
                    float v = fmaxf(fmaf(a[r], sv[r], bv[r]), 0.f);
                    int byte = t * 128 + ((c4 * 2) ^ ((t & 7) << 4));
                    *(ushort_t*)(lsT + byte) = f2bf(v);
                }
            }
        }
    }
    __syncthreads();

    // conv2 MFMA: l2[c][t] = sigmoid( sum_{c4} wl2bf[c][c4] * lsT[t][c4] ), K = 64
    {
        f32x4 acc[4][2];
#pragma unroll
        for (int mtl = 0; mtl < 4; ++mtl)
#pragma unroll
            for (int nt = 0; nt < 2; ++nt) acc[mtl][nt] = (f32x4){0.f, 0.f, 0.f, 0.f};
        int swz = ((mrow & 7) << 4);
#pragma unroll
        for (int kk = 0; kk < 64; kk += 32) {
            short8 af[4], bfr[2];
#pragma unroll
            for (int mtl = 0; mtl < 4; ++mtl)
                af[mtl] = *(const short8*)(wl2bf + (wave * 64 + mtl * 16 + mrow) * 64 + kk + kof);
#pragma unroll
            for (int nt = 0; nt < 2; ++nt)
                bfr[nt] = *(const short8*)(lsT + (nt * 16 + mrow) * 128 + (((kk + kof) * 2) ^ swz));
#pragma unroll
            for (int mtl = 0; mtl < 4; ++mtl)
#pragma unroll
                for (int nt = 0; nt < 2; ++nt)
                    acc[mtl][nt] = __builtin_amdgcn_mfma_f32_16x16x32_bf16(af[mtl], bfr[nt], acc[mtl][nt], 0, 0, 0);
        }
        // sigmoid + store l2out[n][c][t]
#pragma unroll
        for (int nt = 0; nt < 2; ++nt) {
            int t = nt * 16 + (lane & 15);
            if (t < 20) {
#pragma unroll
                for (int mtl = 0; mtl < 4; ++mtl) {
#pragma unroll
                    for (int r = 0; r < 4; ++r) {
                        int c = wave * 64 + mtl * 16 + prow + r;
                        float v = acc[mtl][nt][r];
                        l2out[(n * C_ + c) * T_ + t] = 1.f / (1.f + __expf(-v));
                    }
                }
            }
        }
    }
}

// ---------------- Kernel 3: dyn-conv + bn1 + MFMA 1x1 + bn2, grid (5, N) ----------------
#define YSTRIDE 264   // bf16 elems per yT row: 528 B, 16B-aligned, 2-way-bank (free)

template <int NT>
__device__ __forceinline__ void gemm_pass(const ushort_t* __restrict__ yT,
                                          const ushort_t* __restrict__ wbf,
                                          float* __restrict__ outn,
                                          const int (&ctb)[NT], int ov_idx,
                                          int obase, int mrow, int kof, int prow,
                                          float s2, float b2) {
    f32x4 acc[4][NT];
#pragma unroll
    for (int mt = 0; mt < 4; ++mt)
#pragma unroll
        for (int j = 0; j < NT; ++j) acc[mt][j] = (f32x4){0.f, 0.f, 0.f, 0.f};

#pragma unroll 1
    for (int kk = 0; kk < C_; kk += 32) {
        short8 af[4];
        short8 bfr[NT];
#pragma unroll
        for (int mt = 0; mt < 4; ++mt)
            af[mt] = *(const short8*)(wbf + (obase + mt * 16 + mrow) * C_ + kk + kof);
#pragma unroll
        for (int j = 0; j < NT; ++j)
            bfr[j] = *(const short8*)(yT + (ctb[j] + mrow) * YSTRIDE + kk + kof);
#pragma unroll
        for (int mt = 0; mt < 4; ++mt)
#pragma unroll
            for (int j = 0; j < NT; ++j)
                acc[mt][j] = __builtin_amdgcn_mfma_f32_16x16x32_bf16(af[mt], bfr[j], acc[mt][j], 0, 0, 0);
    }

#pragma unroll
    for (int mt = 0; mt < 4; ++mt) {
#pragma unroll
        for (int r = 0; r < 4; ++r) {
            int lsrc = mt * 16 + prow + r;            // lane owning channel obase+lsrc
            float s2w = __shfl(s2, lsrc);
            float b2w = __shfl(b2, lsrc);
            float* orow = outn + (size_t)(obase + lsrc) * VT_;
#pragma unroll
            for (int j = 0; j < NT; ++j) {
                bool skip = (j == ov_idx) && (mrow < 12);   // overlap tile: dup p 84..95
                if (!skip) {
                    float vr = fmaxf(fmaf(acc[mt][j][r], s2w, b2w), 0.f);
                    orow[ctb[j] + mrow] = vr;
                }
            }
        }
    }
}

__global__ __launch_bounds__(256, 3) void k_main(const float* __restrict__ x,
                                                 const ushort_t* __restrict__ wbf,
                                                 const float* __restrict__ bn1p,
                                                 const float* __restrict__ bn2p,
                                                 const float* __restrict__ kern,
                                                 const float* __restrict__ l2g,
                                                 float* __restrict__ out) {
    __shared__ __align__(16) ushort_t yT[100 * YSTRIDE];   // 52800 B -> 3 blocks/CU

    int tid = threadIdx.x;
    int n = blockIdx.y;
    int vblk = blockIdx.x;
    const float* xn = x + (size_t)n * (C_ * V_ * T_) + vblk * 100;

    float s1, b1, k0, k1, k2, s2, b2, l2r[20];
    {
        int c = tid;
        float g1 = bn1p[c], be1 = bn1p[256 + c];
        float m1 = bn1p[512 + c], v1 = bn1p[768 + c];
        s1 = g1 * rsqrtf(v1 + EPS_);
        b1 = be1 - m1 * s1;
        float g2 = bn2p[c], be2 = bn2p[256 + c];
        float m2 = bn2p[512 + c], v2 = bn2p[768 + c];
        s2 = g2 * rsqrtf(v2 + EPS_);
        b2 = be2 - m2 * s2;
        const float* kp = kern + (n * C_ + c) * 3;
        k0 = kp[0]; k1 = kp[1]; k2 = kp[2];
        const f32x4* lp = (const f32x4*)(l2g + (n * C_ + c) * T_);
#pragma unroll
        for (int q = 0; q < 5; ++q) {
            f32x4 v = lp[q];
            l2r[q*4+0] = v.x; l2r[q*4+1] = v.y; l2r[q*4+2] = v.z; l2r[q*4+3] = v.w;
        }
    }

    // invariant per-q offsets: id -> (c = id/5, qq = id%5)
    int offg[5], offs[5];
#pragma unroll
    for (int q = 0; q < 5; ++q) {
        int id = q * 256 + tid;
        int c = id / 5, qq = id % 5;
        offg[q] = c * VT_ + qq * 4;   // global: + vl*20
        offs[q] = c * 20 + qq * 4;    // ushort idx within xs
    }

    // ---- staging: depth-2 software pipeline (loads for vl+2 in flight),
    //      lgkmcnt-only barriers, LDS(bf16) transpose -> conv -> yT ----
    f32x4 ld[2][5];
#pragma unroll
    for (int q = 0; q < 5; ++q) ld[0][q] = *(const f32x4*)(xn + offg[q]);
#pragma unroll
    for (int q = 0; q < 5; ++q) ld[1][q] = *(const f32x4*)(xn + offg[q] + 20);

#pragma unroll
    for (int vl = 0; vl < 5; ++vl) {
        const int cur = vl & 1;
        ushort_t* xs = yT + vl * 20 * YSTRIDE;   // aliases this vl's future yT rows
#pragma unroll
        for (int q = 0; q < 5; ++q) {
            us4 o; o.x = f2bf(ld[cur][q].x); o.y = f2bf(ld[cur][q].y);
            o.z = f2bf(ld[cur][q].z); o.w = f2bf(ld[cur][q].w);
            *(us4*)(xs + offs[q]) = o;
        }
        if (vl < 3) {   // refill this buffer with vl+2's data (stays in flight 2 iters)
#pragma unroll
            for (int q = 0; q < 5; ++q)
                ld[cur][q] = *(const f32x4*)(xn + offg[q] + (vl + 2) * 20);
        }
        bar_lds();                                // xs visible; vmcnt NOT drained
        float a[22];
        a[0] = 0.f; a[21] = 0.f;
        {
            const ushort_t* xrow = xs + tid * 20;
#pragma unroll
            for (int qq = 0; qq < 5; ++qq) {
                us4 u = *(const us4*)(xrow + qq * 4);
                a[qq*4 + 1] = bf2f(u.x) + l2r[qq*4 + 0];
                a[qq*4 + 2] = bf2f(u.y) + l2r[qq*4 + 1];
                a[qq*4 + 3] = bf2f(u.z) + l2r[qq*4 + 2];
                a[qq*4 + 4] = bf2f(u.w) + l2r[qq*4 + 3];
            }
        }
        bar_lds();                                // all xs reads done; region becomes yT
        {
            ushort_t* yrow = yT + vl * 20 * YSTRIDE + tid;
#pragma unroll
            for (int t = 0; t < 20; ++t) {
                float z = fmaf(k0, a[t], fmaf(k1, a[t + 1], k2 * a[t + 2]));
                yrow[t * YSTRIDE] = f2bf(fmaxf(fmaf(z, s1, b1), 0.f));
            }
        }
    }
    bar_lds();   // yT complete for all waves

    // ---- MFMA: out[o,p] = sum_c Wc2[o,c] * y[c,p], split into 2 ct-passes ----
    int lane = tid & 63;
    int wave = tid >> 6;
    int mrow = lane & 15;
    int kof = (lane >> 4) * 8;
    int prow = (lane >> 4) * 4;
    int obase = wave * 64;
    float* outn = out + (size_t)n * (O_ * VT_) + vblk * 100;

    {
        const int ctb0[4] = {0, 16, 32, 48};      // p 0..63
        gemm_pass<4>(yT, wbf, outn, ctb0, -1, obase, mrow, kof, prow, s2, b2);
    }
    {
        const int ctb1[3] = {64, 80, 84};         // p 64..95 + overlap tile (96..99)
        gemm_pass<3>(yT, wbf, outn, ctb1, 2, obase, mrow, kof, prow, s2, b2);
    }
}

extern "C" void kernel_launch(void* const* d_in, const int* in_sizes, int n_in,
                              void* d_out, int out_size, void* d_ws, size_t ws_size,
                              hipStream_t stream) {
    const float* x   = (const float*)d_in[0];
    const float* Wg1 = (const float*)d_in[1];
    const float* Wg2 = (const float*)d_in[2];
    const float* Wl1 = (const float*)d_in[3];
    const float* Wl2 = (const float*)d_in[4];
    const float* Wc2 = (const float*)d_in[5];
    const float* bng = (const float*)d_in[6];
    const float* bnl = (const float*)d_in[7];
    const float* bn1p = (const float*)d_in[8];
    const float* bn2p = (const float*)d_in[9];
    float* out = (float*)d_out;

    float* ws = (float*)d_ws;
    float* pooled = ws;                                   // N*C*T = 1310720 f
    float* kern   = ws + 1310720;                         // N*C*3 = 196608 f
    float* l2g    = ws + 1310720 + 196608;                // N*C*T = 1310720 f
    ushort_t* wbf   = (ushort_t*)(ws + 2818048);          // 65536 bf16 (32768 f)
    ushort_t* wl2bf = (ushort_t*)(ws + 2818048 + 32768);  // 16384 bf16 (8192 f)
    ushort_t* awl   = (ushort_t*)(ws + 2818048 + 40960);  // 49152 bf16 (24576 f)

    k_pool<<<dim3(8464), dim3(256), 0, stream>>>(x, pooled, Wc2, wbf, Wl1, awl, Wl2, wl2bf);
    k_gl<<<dim3(N_), dim3(256), 0, stream>>>(pooled, Wg1, Wg2, bng, bnl, awl, wl2bf, kern, l2g);
    k_main<<<dim3(5, N_), dim3(256), 0, stream>>>(x, wbf, bn1p, bn2p, kern, l2g, out);
}